// Round 3
// baseline (189.492 us; speedup 1.0000x reference)
//
#include <hip/hip_runtime.h>
#include <hip/hip_bf16.h>
#include <stdint.h>

// Problem constants: B=2, S=2048, D=768, H=12, DK=64
typedef __attribute__((ext_vector_type(8))) short bf16x8;
typedef __attribute__((ext_vector_type(4))) short bf16x4;
typedef __attribute__((ext_vector_type(4))) float f32x4;
typedef __attribute__((ext_vector_type(16))) float f32x16;
typedef __attribute__((ext_vector_type(4))) unsigned short u16x4;

__device__ __forceinline__ unsigned short f2bf(float x) {
  union { __hip_bfloat16 h; unsigned short s; } u;
  u.h = __float2bfloat16(x);
  return u.s;
}
__device__ __forceinline__ unsigned int cvtpk(float lo, float hi) {
  unsigned int r;
  asm("v_cvt_pk_bf16_f32 %0, %1, %2" : "=v"(r) : "v"(lo), "v"(hi));
  return r;
}

// ---------------- mask pack: int32 [B,1,S,S] -> bit per key ----------------
__global__ __launch_bounds__(256) void maskpack_kernel(const int* __restrict__ mask,
                                                       unsigned int* __restrict__ mp,
                                                       int total) {
  int i = blockIdx.x * blockDim.x + threadIdx.x;
  const int lane = threadIdx.x & 63;
  const int stride = gridDim.x * blockDim.x;
  for (; i < total; i += stride) {
    unsigned long long b = __ballot(mask[i] != 0);
    if (lane == 0)       mp[i >> 5] = (unsigned int)b;
    else if (lane == 32) mp[i >> 5] = (unsigned int)(b >> 32);
  }
}

// ---------------- projection GEMM: y = X @ W^T ----------------
// q (z==0): scaled by log2(e)/8, layout [B,H,S,64].
// k (z==1): layout [B,H,S,64].  v (z==2): TRANSPOSED layout [B,H,64,S].
__global__ __launch_bounds__(256) void proj_gemm(
    const float* __restrict__ Qi, const float* __restrict__ Ki, const float* __restrict__ Vi,
    const float* __restrict__ Wq, const float* __restrict__ Wk, const float* __restrict__ Wv,
    unsigned short* __restrict__ qo, unsigned short* __restrict__ ko, unsigned short* __restrict__ vo) {
  constexpr int LDT = 56;
  __shared__ unsigned short As[128][LDT];
  __shared__ unsigned short Bs[128][LDT];
  const int z = blockIdx.z;
  const float* A = (z == 0) ? Qi : (z == 1) ? Ki : Vi;
  const float* W = (z == 0) ? Wq : (z == 1) ? Wk : Wv;
  const int m0 = blockIdx.y * 128, n0 = blockIdx.x * 128;
  const int t = threadIdx.x, lane = t & 63, w = t >> 6;
  const int wr = w >> 1, wc = w & 1;
  const int fr = lane & 15, fg = (lane >> 4) * 8;
  const int srow = t >> 3, sseg = t & 7;
  f32x4 acc[4][4] = {};
  for (int kk = 0; kk < 768; kk += 32) {
    for (int pp = 0; pp < 4; ++pp) {
      int row = srow + pp * 32;
      float4 fa = *(const float4*)&A[(size_t)(m0 + row) * 768 + kk + sseg * 4];
      float4 fb = *(const float4*)&W[(size_t)(n0 + row) * 768 + kk + sseg * 4];
      bf16x4 pa = {(short)f2bf(fa.x), (short)f2bf(fa.y), (short)f2bf(fa.z), (short)f2bf(fa.w)};
      bf16x4 pb = {(short)f2bf(fb.x), (short)f2bf(fb.y), (short)f2bf(fb.z), (short)f2bf(fb.w)};
      *(bf16x4*)&As[row][sseg * 4] = pa;
      *(bf16x4*)&Bs[row][sseg * 4] = pb;
    }
    __syncthreads();
    bf16x8 af[4], bfr[4];
    for (int i = 0; i < 4; ++i) af[i]  = *(const bf16x8*)&As[wr * 64 + i * 16 + fr][fg];
    for (int i = 0; i < 4; ++i) bfr[i] = *(const bf16x8*)&Bs[wc * 64 + i * 16 + fr][fg];
    for (int i = 0; i < 4; ++i)
      for (int j = 0; j < 4; ++j)
        acc[i][j] = __builtin_amdgcn_mfma_f32_16x16x32_bf16(af[i], bfr[j], acc[i][j], 0, 0, 0);
    __syncthreads();
  }
  if (z == 2) {
    for (int i = 0; i < 4; ++i)
      for (int j = 0; j < 4; ++j) {
        int m = m0 + wr * 64 + i * 16 + (lane >> 4) * 4;
        int n = n0 + wc * 64 + j * 16 + fr;
        int b = m >> 11, s = m & 2047, hd = n >> 6, dk = n & 63;
        u16x4 pk;
        for (int r = 0; r < 4; ++r) pk[r] = f2bf(acc[i][j][r]);
        *(u16x4*)&vo[((size_t)(b * 12 + hd) * 64 + dk) * 2048 + s] = pk;
      }
  } else {
    unsigned short* O = (z == 0) ? qo : ko;
    const float scale = (z == 0) ? 0.18033688f : 1.0f;  // log2(e)/8 for q
    for (int i = 0; i < 4; ++i)
      for (int j = 0; j < 4; ++j)
        for (int r = 0; r < 4; ++r) {
          int m = m0 + wr * 64 + i * 16 + (lane >> 4) * 4 + r;
          int n = n0 + wc * 64 + j * 16 + fr;
          int b = m >> 11, s = m & 2047, hd = n >> 6, dk = n & 63;
          O[((size_t)(b * 12 + hd) * 2048 + s) * 64 + dk] = f2bf(acc[i][j][r] * scale);
        }
  }
}

// ---------------- output GEMM: out = attn(bf16) @ W_O^T -> fp32 ----------------
__global__ __launch_bounds__(256) void out_gemm(
    const unsigned short* __restrict__ Ain, const float* __restrict__ W,
    float* __restrict__ Out) {
  constexpr int LDT = 56;
  __shared__ unsigned short As[128][LDT];
  __shared__ unsigned short Bs[128][LDT];
  const int m0 = blockIdx.y * 128, n0 = blockIdx.x * 128;
  const int t = threadIdx.x, lane = t & 63, w = t >> 6;
  const int wr = w >> 1, wc = w & 1;
  const int fr = lane & 15, fg = (lane >> 4) * 8;
  f32x4 acc[4][4] = {};
  for (int kk = 0; kk < 768; kk += 32) {
    {
      int row = t >> 2, seg = t & 3;
      for (int pp = 0; pp < 2; ++pp) {
        bf16x8 va = *(const bf16x8*)&Ain[(size_t)(m0 + row + pp * 64) * 768 + kk + seg * 8];
        *(bf16x8*)&As[row + pp * 64][seg * 8] = va;
      }
      int row2 = t >> 3, seg2 = t & 7;
      for (int pp = 0; pp < 4; ++pp) {
        float4 fb = *(const float4*)&W[(size_t)(n0 + row2 + pp * 32) * 768 + kk + seg2 * 4];
        bf16x4 pb = {(short)f2bf(fb.x), (short)f2bf(fb.y), (short)f2bf(fb.z), (short)f2bf(fb.w)};
        *(bf16x4*)&Bs[row2 + pp * 32][seg2 * 4] = pb;
      }
    }
    __syncthreads();
    bf16x8 af[4], bfr[4];
    for (int i = 0; i < 4; ++i) af[i]  = *(const bf16x8*)&As[wr * 64 + i * 16 + fr][fg];
    for (int i = 0; i < 4; ++i) bfr[i] = *(const bf16x8*)&Bs[wc * 64 + i * 16 + fr][fg];
    for (int i = 0; i < 4; ++i)
      for (int j = 0; j < 4; ++j)
        acc[i][j] = __builtin_amdgcn_mfma_f32_16x16x32_bf16(af[i], bfr[j], acc[i][j], 0, 0, 0);
    __syncthreads();
  }
  for (int i = 0; i < 4; ++i)
    for (int j = 0; j < 4; ++j)
      for (int r = 0; r < 4; ++r) {
        int m = m0 + wr * 64 + i * 16 + (lane >> 4) * 4 + r;
        int n = n0 + wc * 64 + j * 16 + fr;
        Out[(size_t)m * 768 + n] = acc[i][j][r];
      }
}

// ---------------- flash attention: split-K x4, no LDS staging, direct-L2 ----------------
// Block = 4 waves, all on the same 32 q-rows; wave w owns key tiles [w*8, w*8+8).
// S^T = K.Q^T, O^T = V^T.P^T (32x32x16 MFMA). Lane-local softmax stats.
// Partials (m,l,acc) merged through LDS at the end (flash-decoding style).
// XCD swizzle: 3 heads per XCD -> per-XCD K/V working set 1.5MB (L2-resident).
__global__ __launch_bounds__(256) void attn_kernel(
    const unsigned short* __restrict__ qh, const unsigned short* __restrict__ kh,
    const unsigned short* __restrict__ vh, const unsigned int* __restrict__ mp,
    unsigned short* __restrict__ ao) {
  __shared__ float Sacc[4][32][64];
  __shared__ float Sm[4][64];
  __shared__ float Sl[4][64];
  const int t = threadIdx.x, lane = t & 63, w = t >> 6;
  // XCD-aware decomposition: 1536 blocks = 8 XCDs x (3 heads x 64 q-blocks)
  const int bid = blockIdx.x;
  const int xcd = bid & 7, ixd = bid >> 3;
  const int bh = xcd * 3 + (ixd >> 6);
  const int qb = ixd & 63;
  const int bb = bh / 12, hh = bh % 12;
  const int q0 = qb * 32;
  const int qc = lane & 31, h = lane >> 5;
  const int q = q0 + qc;
  // Q B-fragments (pre-scaled by log2e/8): B[k][q], k = kc*16 + h*8 + j
  const unsigned short* qrow = qh + ((size_t)bh * 2048 + q) * 64;
  bf16x8 bq[4];
#pragma unroll
  for (int kc = 0; kc < 4; ++kc) bq[kc] = *(const bf16x8*)(qrow + kc * 16 + h * 8);
  const unsigned int* mrow = mp + ((size_t)bb * 2048 + q) * 64;
  const unsigned short* kgb = kh + (size_t)bh * 2048 * 64;
  const unsigned short* vgb = vh + (size_t)bh * 64 * 2048;  // V^T: [64][2048]
  f32x16 acc0 = {}, acc1 = {};
  float m_run = -1e30f, l_run = 0.f;

  for (int it = 0; it < 8; ++it) {
    const int kt = (w * 8 + it) * 64;
    // ---- K A-frags direct from L2: A[m=key][k] ----
    bf16x8 ka0[4], ka1[4];
#pragma unroll
    for (int kc = 0; kc < 4; ++kc) {
      ka0[kc] = *(const bf16x8*)(kgb + (size_t)(kt + qc) * 64 + (kc * 2 + h) * 8);
      ka1[kc] = *(const bf16x8*)(kgb + (size_t)(kt + 32 + qc) * 64 + (kc * 2 + h) * 8);
    }
    f32x16 sc0 = {}, sc1 = {};
#pragma unroll
    for (int kc = 0; kc < 4; ++kc) {
      sc0 = __builtin_amdgcn_mfma_f32_32x32x16_bf16(ka0[kc], bq[kc], sc0, 0, 0, 0);
      sc1 = __builtin_amdgcn_mfma_f32_32x32x16_bf16(ka1[kc], bq[kc], sc1, 0, 0, 0);
    }
    // ---- V A-frags (issued here; L2 latency hidden under softmax) ----
    bf16x8 va0[4], va1[4];
#pragma unroll
    for (int kf = 0; kf < 4; ++kf) {
      va0[kf] = *(const bf16x8*)(vgb + (size_t)qc * 2048 + kt + (kf * 2 + h) * 8);
      va1[kf] = *(const bf16x8*)(vgb + (size_t)(32 + qc) * 2048 + kt + (kf * 2 + h) * 8);
    }
    // ---- mask: one u64 per q-row, extract per-half words ----
    unsigned long long mw = *(const unsigned long long*)(mrow + (kt >> 5));
    unsigned int lo32 = (unsigned int)mw, hi32 = (unsigned int)(mw >> 32);
    unsigned int wl = __builtin_amdgcn_alignbit(hi32, lo32, 4 * h);  // (mw>>4h) low word
    unsigned int whd = hi32 >> (4 * h);                              // (mw>>(32+4h)) low word
#pragma unroll
    for (int r = 0; r < 16; ++r) {
      const int sh = (r & 3) + 8 * (r >> 2);
      sc0[r] = ((wl >> sh) & 1u) ? sc0[r] : -3.0e38f;
      sc1[r] = ((whd >> sh) & 1u) ? sc1[r] : -3.0e38f;
    }
    // ---- tile max (balanced tree, max3-fusable) ----
    float mA[8];
#pragma unroll
    for (int i = 0; i < 8; ++i)
      mA[i] = fmaxf(fmaxf(sc0[i], sc0[i + 8]), fmaxf(sc1[i], sc1[i + 8]));
    float mB0 = fmaxf(mA[0], mA[4]), mB1 = fmaxf(mA[1], mA[5]);
    float mB2 = fmaxf(mA[2], mA[6]), mB3 = fmaxf(mA[3], mA[7]);
    float m1 = fmaxf(fmaxf(mB0, mB1), fmaxf(mB2, mB3));
    float tmax = fmaxf(m1, __shfl_xor(m1, 32, 64));
    // ---- T13 defer-rescale: only rescale when max grew by > 8 (log2 domain) ----
    if (__any(tmax > m_run + 8.0f)) {
      float mnew = fmaxf(m_run, tmax);
      float scl = exp2f(m_run - mnew);
      m_run = mnew;
      l_run *= scl;
#pragma unroll
      for (int e = 0; e < 16; ++e) { acc0[e] *= scl; acc1[e] *= scl; }
    }
    // ---- p = exp2(s - m), sum tree ----
#pragma unroll
    for (int r = 0; r < 16; ++r) {
      sc0[r] = exp2f(sc0[r] - m_run);
      sc1[r] = exp2f(sc1[r] - m_run);
    }
    float sA[8];
#pragma unroll
    for (int i = 0; i < 8; ++i)
      sA[i] = (sc0[i] + sc0[i + 8]) + (sc1[i] + sc1[i + 8]);
    float sB0 = sA[0] + sA[4], sB1 = sA[1] + sA[5], sB2 = sA[2] + sA[6], sB3 = sA[3] + sA[7];
    float s1 = (sB0 + sB1) + (sB2 + sB3);
    l_run += s1 + __shfl_xor(s1, 32, 64);
    // ---- PV: O^T += V^T . P^T; P->bf16 via cvt_pk, redistributed via permlane32_swap ----
#define PVQ(P, OFF, A0, A1) { \
    unsigned int a0 = cvtpk(P[OFF + 0], P[OFF + 1]), a1 = cvtpk(P[OFF + 2], P[OFF + 3]); \
    unsigned int b0 = cvtpk(P[OFF + 4], P[OFF + 5]), b1 = cvtpk(P[OFF + 6], P[OFF + 7]); \
    asm("v_permlane32_swap_b32 %0, %1" : "+v"(a0), "+v"(b0)); \
    asm("v_permlane32_swap_b32 %0, %1" : "+v"(a1), "+v"(b1)); \
    union { unsigned int u[4]; bf16x8 v; } bfu; \
    bfu.u[0] = a0; bfu.u[1] = a1; bfu.u[2] = b0; bfu.u[3] = b1; \
    acc0 = __builtin_amdgcn_mfma_f32_32x32x16_bf16(A0, bfu.v, acc0, 0, 0, 0); \
    acc1 = __builtin_amdgcn_mfma_f32_32x32x16_bf16(A1, bfu.v, acc1, 0, 0, 0); }
    PVQ(sc0, 0, va0[0], va1[0]);
    PVQ(sc0, 8, va0[1], va1[1]);
    PVQ(sc1, 0, va0[2], va1[2]);
    PVQ(sc1, 8, va0[3], va1[3]);
#undef PVQ
  }
  // ---- merge 4 split-K partials through LDS ----
  Sm[w][lane] = m_run;
  Sl[w][lane] = l_run;
#pragma unroll
  for (int e = 0; e < 16; ++e) Sacc[w][e][lane] = acc0[e];
#pragma unroll
  for (int e = 0; e < 16; ++e) Sacc[w][16 + e][lane] = acc1[e];
  __syncthreads();
  float pm0 = Sm[0][lane], pm1 = Sm[1][lane], pm2 = Sm[2][lane], pm3 = Sm[3][lane];
  float M = fmaxf(fmaxf(pm0, pm1), fmaxf(pm2, pm3));
  float w0 = exp2f(pm0 - M), w1 = exp2f(pm1 - M), w2 = exp2f(pm2 - M), w3 = exp2f(pm3 - M);
  float L = Sl[0][lane] * w0 + Sl[1][lane] * w1 + Sl[2][lane] * w2 + Sl[3][lane] * w3;
  float inv = (L > 0.f) ? 1.0f / L : 0.f;
  unsigned short* orow = ao + ((size_t)bb * 2048 + q) * 768 + hh * 64;
#pragma unroll
  for (int g = 0; g < 2; ++g) {
    const int e0 = w * 8 + g * 4;
    const int base = (e0 >= 16) ? 32 : 0;
    const int er0 = e0 & 15;
    const int d0 = base + 8 * (er0 >> 2) + 4 * h;
    u16x4 pk4;
#pragma unroll
    for (int j = 0; j < 4; ++j) {
      float v = (Sacc[0][e0 + j][lane] * w0 + Sacc[1][e0 + j][lane] * w1 +
                 Sacc[2][e0 + j][lane] * w2 + Sacc[3][e0 + j][lane] * w3) * inv;
      pk4[j] = f2bf(v);
    }
    *(u16x4*)&orow[d0] = pk4;
  }
}

extern "C" void kernel_launch(void* const* d_in, const int* in_sizes, int n_in,
                              void* d_out, int out_size, void* d_ws, size_t ws_size,
                              hipStream_t stream) {
  const float* Q  = (const float*)d_in[0];
  const float* K  = (const float*)d_in[1];
  const float* V  = (const float*)d_in[2];
  const int*   mask = (const int*)d_in[3];
  const float* WQ = (const float*)d_in[4];
  const float* WK = (const float*)d_in[5];
  const float* WV = (const float*)d_in[6];
  const float* WO = (const float*)d_in[7];
  float* out = (float*)d_out;

  char* ws = (char*)d_ws;
  unsigned short* qh = (unsigned short*)(ws + 0);          // [B,H,S,64] bf16 (pre-scaled)
  unsigned short* kh = (unsigned short*)(ws + 6291456);    // [B,H,S,64] bf16
  unsigned short* vh = (unsigned short*)(ws + 12582912);   // [B,H,64,S] bf16 (transposed)
  unsigned short* ao = (unsigned short*)(ws + 18874368);   // [B,S,D] bf16
  unsigned int*   mp = (unsigned int*)(ws + 25165824);     // bitmask

  maskpack_kernel<<<dim3(2048), 256, 0, stream>>>(mask, mp, 2 * 2048 * 2048);
  proj_gemm<<<dim3(6, 32, 3), 256, 0, stream>>>(Q, K, V, WQ, WK, WV, qh, kh, vh);
  attn_kernel<<<dim3(1536), 256, 0, stream>>>(qh, kh, vh, mp, ao);
  out_gemm<<<dim3(6, 32), 256, 0, stream>>>(ao, WO, out);
}